// Round 6
// baseline (404.370 us; speedup 1.0000x reference)
//
#include <hip/hip_runtime.h>
#include <hip/hip_bf16.h>

typedef short short8 __attribute__((ext_vector_type(8)));
typedef float floatx4 __attribute__((ext_vector_type(4)));

#define B_  256
#define T_  512
#define D_  64
#define L_  32
#define H_  128
#define PXS 516   // pre_x row stride (floats); packed [t][col*4+e] -> 0 conflicts (R4-verified)

__device__ inline short f2bf(float f) {
    __hip_bfloat16 h = __float2bfloat16(f);
    union { __hip_bfloat16 h; short s; } u;
    u.h = h;
    return u.s;
}

__device__ inline float bf2f(short s) {
    union { float f; unsigned u; } u;
    u.u = ((unsigned)(unsigned short)s) << 16;
    return u.f;
}

// packed 2xfp32 -> 2xbf16 (v_cvt_pk path)
__device__ inline unsigned pk2bf(float a, float b) {
    union { __hip_bfloat162 v; unsigned u; } u;
    u.v = __float22bfloat162_rn(float2{a, b});
    return u.u;
}

__device__ inline float fast_sigmoid(float x) {
    return __builtin_amdgcn_rcpf(1.0f + __expf(-x));
}

__device__ inline float fast_tanh(float x) {
    float e = __expf(-2.0f * x);
    return 2.0f * __builtin_amdgcn_rcpf(1.0f + e) - 1.0f;
}

// Barrier draining ONLY lgkmcnt — global loads stay in flight across it.
__device__ inline void block_sync_lds() {
    asm volatile("s_waitcnt lgkmcnt(0)\n\ts_barrier" ::: "memory");
}

// One block per batch element; 512 threads = 8 waves; 1 block/CU.
// Wave w owns hidden cols [16w,16w+16) x 4 gates -> i/f/g/o of a column in one
// lane's accumulators -> in-register EW; c stays in registers.
// Per step: ONE lgkm-only barrier; 16 INDEPENDENT recurrent MFMAs + add-tree
// (no 2-deep MFMA chain on the critical path). Window duties staggered:
// tw==11 x prefetch (reg-direct, 4-step cover), tw==14 out-dot via MFMA
// (M=16 timesteps x K=128, replaces 12 serial shuffles), tw==15 x@Wih MFMA +
// packed-cvt + pre_x dump. No global stores in the loop.
__global__ __launch_bounds__(512, 2) void tamlstm_kernel(
    const float* __restrict__ xd,    // [B,T,D]
    const float* __restrict__ xs,    // [B,L]
    const float* __restrict__ Wih,   // [4H,D]
    const float* __restrict__ Whh,   // [4H,H]
    const float* __restrict__ Wzh,   // [4H,L]
    const float* __restrict__ bias,  // [4H]
    const float* __restrict__ Wout,  // [1,H]
    const float* __restrict__ bout,  // [1]
    float* __restrict__ out)         // [B,T]
{
    const int b    = blockIdx.x;
    const int tid  = threadIdx.x;
    const int w    = tid >> 6;    // wave 0..7
    const int lane = tid & 63;
    const int l15  = lane & 15;
    const int q    = lane >> 4;   // quad 0..3

    __shared__ __align__(16) float pre_x[16][PXS];   // 33 KB, wave-local
    __shared__ __align__(16) short h_ring[32][H_];   // 8 KB bf16 h history
    __shared__ __align__(16) float out_lds[T_];      // 2 KB output buffer

    {   // zero h_ring (slot 0 = h_{-1} = 0)
        int* hr = (int*)h_ring;  // 2048 ints
        #pragma unroll
        for (int i = 0; i < 4; ++i) hr[tid + 512 * i] = 0;
    }

    const int col = (w << 4) + l15;                 // hidden column 0..127

    // ---- B-fragments (bf16) in registers ----
    // B-frag element j = W[gate = col + 128e][k = 32s + 8q + j]
    short8 whh[4][4];  // [gate e][k-chunk s], K=128
    short8 wih[4][2];  // [e][s], K=64
    #pragma unroll
    for (int e = 0; e < 4; ++e) {
        const int g = col + (e << 7);
        const float* rh = Whh + g * H_;
        #pragma unroll
        for (int s = 0; s < 4; ++s) {
            const float* p = rh + s * 32 + q * 8;
            short8 v;
            #pragma unroll
            for (int j = 0; j < 8; ++j) v[j] = f2bf(p[j]);
            whh[e][s] = v;
        }
        const float* ri = Wih + g * D_;
        #pragma unroll
        for (int s = 0; s < 2; ++s) {
            const float* p = ri + s * 32 + q * 8;
            short8 v;
            #pragma unroll
            for (int j = 0; j < 8; ++j) v[j] = f2bf(p[j]);
            wih[e][s] = v;
        }
    }
    // W_out B-frag (broadcast over N: element j = wout[32s+8q+j])
    short8 wof[4];
    #pragma unroll
    for (int s = 0; s < 4; ++s) {
        short8 v;
        #pragma unroll
        for (int j = 0; j < 8; ++j) v[j] = f2bf(Wout[s * 32 + q * 8 + j]);
        wof[s] = v;
    }
    const float bo = bout[0];

    // ---- static part: bias + x_static @ Wzh^T (folded into pre_x at dump) ----
    float S[4];
    const float* xsb = xs + b * L_;
    #pragma unroll
    for (int e = 0; e < 4; ++e) {
        const int g = col + (e << 7);
        const float* wz = Wzh + g * L_;
        float a = bias[g];
        for (int l = 0; l < L_; ++l) a += xsb[l] * wz[l];
        S[e] = a;
    }

    const float* xb = xd + (size_t)b * T_ * D_;

    // ---- prologue: window-0 pre_x ----
    {
        const float* xr = xb + l15 * D_;            // timestep row l15
        float4 u0 = *(const float4*)(xr + q * 8);
        float4 u1 = *(const float4*)(xr + q * 8 + 4);
        float4 u2 = *(const float4*)(xr + 32 + q * 8);
        float4 u3 = *(const float4*)(xr + 32 + q * 8 + 4);
        union { short8 s; unsigned u[4]; } a0, a1;
        a0.u[0] = pk2bf(u0.x, u0.y); a0.u[1] = pk2bf(u0.z, u0.w);
        a0.u[2] = pk2bf(u1.x, u1.y); a0.u[3] = pk2bf(u1.z, u1.w);
        a1.u[0] = pk2bf(u2.x, u2.y); a1.u[1] = pk2bf(u2.z, u2.w);
        a1.u[2] = pk2bf(u3.x, u3.y); a1.u[3] = pk2bf(u3.z, u3.w);
        #pragma unroll
        for (int e = 0; e < 4; ++e) {
            floatx4 aw = __builtin_amdgcn_mfma_f32_16x16x32_bf16(a0.s, wih[e][0],
                             (floatx4){0.f, 0.f, 0.f, 0.f}, 0, 0, 0);
            aw = __builtin_amdgcn_mfma_f32_16x16x32_bf16(a1.s, wih[e][1], aw, 0, 0, 0);
            #pragma unroll
            for (int r = 0; r < 4; ++r)
                pre_x[q * 4 + r][(col << 2) + e] = aw[r] + S[e];
        }
    }

    float c = 0.0f;
    float4 xv0, xv1, xv2, xv3;     // in-flight x A-rows for next window

    __syncthreads();               // h_ring zero visible

    for (int t = 0; t < T_; ++t) {
        const int tw = t & 15;

        // ---- h A-frag reads first (px after; progressive lgkm waits) ----
        const short8* hp = (const short8*)h_ring[t & 31];
        short8 af0 = hp[q];
        short8 af1 = hp[4 + q];
        short8 af2 = hp[8 + q];
        short8 af3 = hp[12 + q];
        floatx4 px = *(const floatx4*)&pre_x[tw][col << 2];

        // ---- 16 INDEPENDENT recurrent MFMAs (no chaining) ----
        floatx4 m0[4], m1[4], m2[4], m3[4];
        #pragma unroll
        for (int e = 0; e < 4; ++e) {
            m0[e] = __builtin_amdgcn_mfma_f32_16x16x32_bf16(af0, whh[e][0],
                        (floatx4){0.f, 0.f, 0.f, 0.f}, 0, 0, 0);
            m1[e] = __builtin_amdgcn_mfma_f32_16x16x32_bf16(af1, whh[e][1],
                        (floatx4){0.f, 0.f, 0.f, 0.f}, 0, 0, 0);
            m2[e] = __builtin_amdgcn_mfma_f32_16x16x32_bf16(af2, whh[e][2],
                        (floatx4){0.f, 0.f, 0.f, 0.f}, 0, 0, 0);
            m3[e] = __builtin_amdgcn_mfma_f32_16x16x32_bf16(af3, whh[e][3],
                        (floatx4){0.f, 0.f, 0.f, 0.f}, 0, 0, 0);
        }

        // ---- duty: x prefetch (reg-direct; 4 steps of cover, vmcnt survives
        //      lgkm-only barriers) ----
        if (tw == 11 && t + 21 <= T_) {
            const float* xr = xb + (size_t)(t + 5 + l15) * D_;  // t0+16+l15
            xv0 = *(const float4*)(xr + q * 8);
            xv1 = *(const float4*)(xr + q * 8 + 4);
            xv2 = *(const float4*)(xr + 32 + q * 8);
            xv3 = *(const float4*)(xr + 32 + q * 8 + 4);
        }

        // ---- duty: deferred out-dot for window W-1 via MFMA (all waves,
        //      redundant, benign same-data LDS write races) ----
        if (tw == 14 && t >= 30) {
            const int tp = (t & ~15) - 16;          // window base
            const short* ap = &h_ring[(tp + l15 + 1) & 31][0];  // row m=l15
            short8 oa0 = *(const short8*)(ap + q * 8);
            short8 oa1 = *(const short8*)(ap + 32 + q * 8);
            short8 oa2 = *(const short8*)(ap + 64 + q * 8);
            short8 oa3 = *(const short8*)(ap + 96 + q * 8);
            floatx4 d0 = __builtin_amdgcn_mfma_f32_16x16x32_bf16(oa0, wof[0],
                             (floatx4){0.f, 0.f, 0.f, 0.f}, 0, 0, 0);
            floatx4 d1 = __builtin_amdgcn_mfma_f32_16x16x32_bf16(oa1, wof[1],
                             (floatx4){0.f, 0.f, 0.f, 0.f}, 0, 0, 0);
            floatx4 d2 = __builtin_amdgcn_mfma_f32_16x16x32_bf16(oa2, wof[2],
                             (floatx4){0.f, 0.f, 0.f, 0.f}, 0, 0, 0);
            floatx4 d3 = __builtin_amdgcn_mfma_f32_16x16x32_bf16(oa3, wof[3],
                             (floatx4){0.f, 0.f, 0.f, 0.f}, 0, 0, 0);
            floatx4 od = (d0 + d1) + (d2 + d3);     // rows 4q+r = timesteps
            if (l15 == 0) {
                floatx4 ov = {od[0] + bo, od[1] + bo, od[2] + bo, od[3] + bo};
                *(floatx4*)&out_lds[tp + q * 4] = ov;
            }
        }

        // ---- EW: add-tree on .x (quads duplicate), S already in px ----
        const float gi = (m0[0].x + m1[0].x) + (m2[0].x + m3[0].x) + px[0];
        const float gf = (m0[1].x + m1[1].x) + (m2[1].x + m3[1].x) + px[1];
        const float gg = (m0[2].x + m1[2].x) + (m2[2].x + m3[2].x) + px[2];
        const float go = (m0[3].x + m1[3].x) + (m2[3].x + m3[3].x) + px[3];
        const float is = fast_sigmoid(gi);
        const float fs = fast_sigmoid(gf);
        const float os = fast_sigmoid(go);
        const float tg = fast_tanh(gg);
        c = fs * c + is * tg;
        const float h = os * fast_tanh(c);

        if (lane < 16) h_ring[(t + 1) & 31][col] = f2bf(h);

        // ---- duty: next window's x@Wih + pre_x dump (wave-local) ----
        if (tw == 15 && t + 1 < T_) {
            union { short8 s; unsigned u[4]; } a0, a1;
            a0.u[0] = pk2bf(xv0.x, xv0.y); a0.u[1] = pk2bf(xv0.z, xv0.w);
            a0.u[2] = pk2bf(xv1.x, xv1.y); a0.u[3] = pk2bf(xv1.z, xv1.w);
            a1.u[0] = pk2bf(xv2.x, xv2.y); a1.u[1] = pk2bf(xv2.z, xv2.w);
            a1.u[2] = pk2bf(xv3.x, xv3.y); a1.u[3] = pk2bf(xv3.z, xv3.w);
            floatx4 aw[4];
            #pragma unroll
            for (int e = 0; e < 4; ++e) {
                aw[e] = __builtin_amdgcn_mfma_f32_16x16x32_bf16(a0.s, wih[e][0],
                            (floatx4){0.f, 0.f, 0.f, 0.f}, 0, 0, 0);
                aw[e] = __builtin_amdgcn_mfma_f32_16x16x32_bf16(a1.s, wih[e][1], aw[e], 0, 0, 0);
            }
            #pragma unroll
            for (int r = 0; r < 4; ++r) {
                floatx4 pk = {aw[0][r] + S[0], aw[1][r] + S[1],
                              aw[2][r] + S[2], aw[3][r] + S[3]};
                *(floatx4*)&pre_x[q * 4 + r][col << 2] = pk;
            }
        }

        block_sync_lds();
    }

    // ---- epilogue: out-dot for final window (t' = 496..511) ----
    {
        const int tp = T_ - 16;
        const short* ap = &h_ring[(tp + l15 + 1) & 31][0];
        short8 oa0 = *(const short8*)(ap + q * 8);
        short8 oa1 = *(const short8*)(ap + 32 + q * 8);
        short8 oa2 = *(const short8*)(ap + 64 + q * 8);
        short8 oa3 = *(const short8*)(ap + 96 + q * 8);
        floatx4 d0 = __builtin_amdgcn_mfma_f32_16x16x32_bf16(oa0, wof[0],
                         (floatx4){0.f, 0.f, 0.f, 0.f}, 0, 0, 0);
        floatx4 d1 = __builtin_amdgcn_mfma_f32_16x16x32_bf16(oa1, wof[1],
                         (floatx4){0.f, 0.f, 0.f, 0.f}, 0, 0, 0);
        floatx4 d2 = __builtin_amdgcn_mfma_f32_16x16x32_bf16(oa2, wof[2],
                         (floatx4){0.f, 0.f, 0.f, 0.f}, 0, 0, 0);
        floatx4 d3 = __builtin_amdgcn_mfma_f32_16x16x32_bf16(oa3, wof[3],
                         (floatx4){0.f, 0.f, 0.f, 0.f}, 0, 0, 0);
        floatx4 od = (d0 + d1) + (d2 + d3);
        if (l15 == 0) {
            floatx4 ov = {od[0] + bo, od[1] + bo, od[2] + bo, od[3] + bo};
            *(floatx4*)&out_lds[tp + q * 4] = ov;
        }
    }
    block_sync_lds();
    out[b * T_ + tid] = out_lds[tid];
}

extern "C" void kernel_launch(void* const* d_in, const int* in_sizes, int n_in,
                              void* d_out, int out_size, void* d_ws, size_t ws_size,
                              hipStream_t stream) {
    const float* xd   = (const float*)d_in[0];
    const float* xs   = (const float*)d_in[1];
    const float* Wih  = (const float*)d_in[2];
    const float* Whh  = (const float*)d_in[3];
    const float* Wzh  = (const float*)d_in[4];
    const float* bias = (const float*)d_in[5];
    const float* Wout = (const float*)d_in[6];
    const float* bout = (const float*)d_in[7];
    float* o = (float*)d_out;
    hipLaunchKernelGGL(tamlstm_kernel, dim3(B_), dim3(512), 0, stream,
                       xd, xs, Wih, Whh, Wzh, bias, Wout, bout, o);
}

// Round 7
// 342.241 us; speedup vs baseline: 1.1815x; 1.1815x over previous
//
#include <hip/hip_runtime.h>
#include <hip/hip_bf16.h>

typedef short short8 __attribute__((ext_vector_type(8)));
typedef float floatx4 __attribute__((ext_vector_type(4)));

#define B_  256
#define T_  512
#define D_  64
#define L_  32
#define H_  128
#define PXS 516   // packed pre_x row stride (floats): [t][col*4+e], 0 conflicts (R4/R5-verified)
#define HRS 136   // h_ring row stride in shorts: 136*2B=272B -> row bank offset 4, breaks R6's 32-way

__device__ inline short f2bf(float f) {
    __hip_bfloat16 h = __float2bfloat16(f);
    union { __hip_bfloat16 h; short s; } u;
    u.h = h;
    return u.s;
}

__device__ inline float fast_sigmoid(float x) {
    return __builtin_amdgcn_rcpf(1.0f + __expf(-x));
}

__device__ inline float fast_tanh(float x) {
    float e = __expf(-2.0f * x);
    return 2.0f * __builtin_amdgcn_rcpf(1.0f + e) - 1.0f;
}

// One block per batch element; 512 threads = 8 waves; 1 block/CU.
// K1 (best: 318us) skeleton. Wave w owns hidden cols [16w,16w+16) x 4 gates ->
// i/f/g/o of a column in one lane's accumulators -> in-register EW.
// Window step (tw==0): wave-0 out-dot for window W-1 via MFMA (conflict-free
// padded ring), stage x, barrier, prefetch next x, window MFMA, packed pre_x
// dump (wave-local, single-buffer). Per step: 4-deep chained MFMAs x4 gates,
// one b128 pre_x read, EW, h write, __syncthreads.
__global__ __launch_bounds__(512, 2) void tamlstm_kernel(
    const float* __restrict__ xd,    // [B,T,D]
    const float* __restrict__ xs,    // [B,L]
    const float* __restrict__ Wih,   // [4H,D]
    const float* __restrict__ Whh,   // [4H,H]
    const float* __restrict__ Wzh,   // [4H,L]
    const float* __restrict__ bias,  // [4H]
    const float* __restrict__ Wout,  // [1,H]
    const float* __restrict__ bout,  // [1]
    float* __restrict__ out)         // [B,T]
{
    const int b    = blockIdx.x;
    const int tid  = threadIdx.x;
    const int w    = tid >> 6;    // wave 0..7
    const int lane = tid & 63;
    const int l15  = lane & 15;
    const int q    = lane >> 4;   // quad 0..3

    __shared__ __align__(16) float pre_x[16][PXS];   // 33 KB, wave-local r/w
    __shared__ __align__(16) short x_lds[16][72];    // 2.25 KB staged x window
    __shared__ __align__(16) short h_ring[32 * HRS]; // 8.5 KB padded bf16 ring
    __shared__ __align__(16) float out_lds[T_];      // 2 KB output buffer

    // zero ring row 0 only (h_{-1}); rows 1..31 are written before read
    if (tid < 64) ((int*)h_ring)[tid] = 0;

    const int col = (w << 4) + l15;                 // hidden column 0..127

    // ---- B-fragments (bf16) in registers ----
    // B-frag element j = W[gate = col + 128e][k = 32s + 8q + j]
    short8 whh[4][4];  // [gate e][k-chunk s], K=128
    short8 wih[4][2];  // [e][s], K=64
    #pragma unroll
    for (int e = 0; e < 4; ++e) {
        const int g = col + (e << 7);
        const float* rh = Whh + g * H_;
        #pragma unroll
        for (int s = 0; s < 4; ++s) {
            const float* p = rh + s * 32 + q * 8;
            short8 v;
            #pragma unroll
            for (int j = 0; j < 8; ++j) v[j] = f2bf(p[j]);
            whh[e][s] = v;
        }
        const float* ri = Wih + g * D_;
        #pragma unroll
        for (int s = 0; s < 2; ++s) {
            const float* p = ri + s * 32 + q * 8;
            short8 v;
            #pragma unroll
            for (int j = 0; j < 8; ++j) v[j] = f2bf(p[j]);
            wih[e][s] = v;
        }
    }
    // W_out B-frag (broadcast over N: element j = wout[32s+8q+j])
    short8 wof[4];
    #pragma unroll
    for (int s = 0; s < 4; ++s) {
        short8 v;
        #pragma unroll
        for (int j = 0; j < 8; ++j) v[j] = f2bf(Wout[s * 32 + q * 8 + j]);
        wof[s] = v;
    }
    const float bo = bout[0];

    // ---- static part: bias + x_static @ Wzh^T (folded into pre_x at dump) ----
    float S[4];
    const float* xsb = xs + b * L_;
    #pragma unroll
    for (int e = 0; e < 4; ++e) {
        const int g = col + (e << 7);
        const float* wz = Wzh + g * L_;
        float a = bias[g];
        for (int l = 0; l < L_; ++l) a += xsb[l] * wz[l];
        S[e] = a;
    }

    const float* xb = xd + (size_t)b * T_ * D_;
    const floatx4 ZERO = {0.f, 0.f, 0.f, 0.f};      // hoisted acc init

    // ---- prologue: stage window 0, compute its pre_x, prefetch window 1 ----
    float xr0, xr1;
    {
        float2 x2 = ((const float2*)xb)[tid];
        unsigned pk = (unsigned)(unsigned short)f2bf(x2.x) |
                      ((unsigned)(unsigned short)f2bf(x2.y) << 16);
        const int e2 = tid * 2;
        *(unsigned*)&x_lds[e2 >> 6][e2 & 63] = pk;
    }
    __syncthreads();   // x_lds + ring row 0 visible
    {
        float2 x2 = ((const float2*)(xb + 16 * D_))[tid];   // window 1 prefetch
        xr0 = x2.x; xr1 = x2.y;
    }
    {
        floatx4 aw[4];
        #pragma unroll
        for (int s = 0; s < 2; ++s) {
            short8 af = *(const short8*)&x_lds[l15][s * 32 + q * 8];
            #pragma unroll
            for (int e = 0; e < 4; ++e)
                aw[e] = __builtin_amdgcn_mfma_f32_16x16x32_bf16(af, wih[e][s],
                            s == 0 ? ZERO : aw[e], 0, 0, 0);
        }
        #pragma unroll
        for (int r = 0; r < 4; ++r) {
            floatx4 pk = {aw[0][r] + S[0], aw[1][r] + S[1],
                          aw[2][r] + S[2], aw[3][r] + S[3]};
            *(floatx4*)&pre_x[q * 4 + r][col << 2] = pk;
        }
    }

    float c = 0.0f;

    for (int t = 0; t < T_; ++t) {
        const int tw = t & 15;

        if (tw == 0 && t > 0) {
            // ---- wave-0: deferred out-dot for window W-1 via MFMA ----
            // A rows m = timesteps tp+m, h in ring slots (tp+1+m)&31 (padded
            // stride -> ~2-way banks). B = wout broadcast. D row 4q+r, col n
            // (all n equal); lanes l15==0 write 16 outputs.
            if (w == 0) {
                const int tp = t - 16;
                const short* ap = &h_ring[((tp + l15 + 1) & 31) * HRS];
                floatx4 d0 = __builtin_amdgcn_mfma_f32_16x16x32_bf16(
                                 *(const short8*)(ap + q * 8),      wof[0], ZERO, 0, 0, 0);
                floatx4 d1 = __builtin_amdgcn_mfma_f32_16x16x32_bf16(
                                 *(const short8*)(ap + 32 + q * 8), wof[1], ZERO, 0, 0, 0);
                floatx4 d2 = __builtin_amdgcn_mfma_f32_16x16x32_bf16(
                                 *(const short8*)(ap + 64 + q * 8), wof[2], ZERO, 0, 0, 0);
                floatx4 d3 = __builtin_amdgcn_mfma_f32_16x16x32_bf16(
                                 *(const short8*)(ap + 96 + q * 8), wof[3], ZERO, 0, 0, 0);
                floatx4 od = (d0 + d1) + (d2 + d3);
                if (l15 == 0) {
                    floatx4 ov = {od[0] + bo, od[1] + bo, od[2] + bo, od[3] + bo};
                    *(floatx4*)&out_lds[tp + q * 4] = ov;
                }
            }

            // ---- stage x window W (regs prefetched 16 steps ago) ----
            {
                unsigned pk = (unsigned)(unsigned short)f2bf(xr0) |
                              ((unsigned)(unsigned short)f2bf(xr1) << 16);
                const int e2 = tid * 2;
                *(unsigned*)&x_lds[e2 >> 6][e2 & 63] = pk;
            }
            __syncthreads();  // x_lds visible (also orders out-dot ring reads)

            // prefetch window W+1 while MFMAs run
            if (t + 16 < T_) {
                float2 x2 = ((const float2*)(xb + (t + 16) * D_))[tid];
                xr0 = x2.x; xr1 = x2.y;
            }

            // ---- window MFMA (M=16 timesteps) + packed dump (wave-local) ----
            floatx4 aw[4];
            #pragma unroll
            for (int s = 0; s < 2; ++s) {
                short8 af = *(const short8*)&x_lds[l15][s * 32 + q * 8];
                #pragma unroll
                for (int e = 0; e < 4; ++e)
                    aw[e] = __builtin_amdgcn_mfma_f32_16x16x32_bf16(af, wih[e][s],
                                s == 0 ? ZERO : aw[e], 0, 0, 0);
            }
            #pragma unroll
            for (int r = 0; r < 4; ++r) {
                floatx4 pk = {aw[0][r] + S[0], aw[1][r] + S[1],
                              aw[2][r] + S[2], aw[3][r] + S[3]};
                *(floatx4*)&pre_x[q * 4 + r][col << 2] = pk;
            }
        }

        // ---- recurrent MFMA: g += h_{t-1} @ Whh^T (4 indep 4-deep chains) ----
        const short8* hp = (const short8*)&h_ring[(t & 31) * HRS];
        short8 af0 = hp[q];
        short8 af1 = hp[4 + q];
        short8 af2 = hp[8 + q];
        short8 af3 = hp[12 + q];
        floatx4 px = *(const floatx4*)&pre_x[tw][col << 2];

        floatx4 acc[4];
        #pragma unroll
        for (int e = 0; e < 4; ++e)
            acc[e] = __builtin_amdgcn_mfma_f32_16x16x32_bf16(af0, whh[e][0], ZERO, 0, 0, 0);
        #pragma unroll
        for (int e = 0; e < 4; ++e)
            acc[e] = __builtin_amdgcn_mfma_f32_16x16x32_bf16(af1, whh[e][1], acc[e], 0, 0, 0);
        #pragma unroll
        for (int e = 0; e < 4; ++e)
            acc[e] = __builtin_amdgcn_mfma_f32_16x16x32_bf16(af2, whh[e][2], acc[e], 0, 0, 0);
        #pragma unroll
        for (int e = 0; e < 4; ++e)
            acc[e] = __builtin_amdgcn_mfma_f32_16x16x32_bf16(af3, whh[e][3], acc[e], 0, 0, 0);

        // ---- elementwise (quads duplicate; S/bias already in px) ----
        const float gi = acc[0].x + px[0];
        const float gf = acc[1].x + px[1];
        const float gg = acc[2].x + px[2];
        const float go = acc[3].x + px[3];
        const float is = fast_sigmoid(gi);
        const float fs = fast_sigmoid(gf);
        const float os = fast_sigmoid(go);
        const float tg = fast_tanh(gg);
        c = fs * c + is * tg;
        const float h = os * fast_tanh(c);

        if (lane < 16) h_ring[((t + 1) & 31) * HRS + col] = f2bf(h);

        __syncthreads();
    }

    // ---- epilogue: out-dot for final window (t' = 496..511), store out ----
    if (w == 0) {
        const int tp = T_ - 16;
        const short* ap = &h_ring[((tp + l15 + 1) & 31) * HRS];
        floatx4 d0 = __builtin_amdgcn_mfma_f32_16x16x32_bf16(
                         *(const short8*)(ap + q * 8),      wof[0], ZERO, 0, 0, 0);
        floatx4 d1 = __builtin_amdgcn_mfma_f32_16x16x32_bf16(
                         *(const short8*)(ap + 32 + q * 8), wof[1], ZERO, 0, 0, 0);
        floatx4 d2 = __builtin_amdgcn_mfma_f32_16x16x32_bf16(
                         *(const short8*)(ap + 64 + q * 8), wof[2], ZERO, 0, 0, 0);
        floatx4 d3 = __builtin_amdgcn_mfma_f32_16x16x32_bf16(
                         *(const short8*)(ap + 96 + q * 8), wof[3], ZERO, 0, 0, 0);
        floatx4 od = (d0 + d1) + (d2 + d3);
        if (l15 == 0) {
            floatx4 ov = {od[0] + bo, od[1] + bo, od[2] + bo, od[3] + bo};
            *(floatx4*)&out_lds[tp + q * 4] = ov;
        }
    }
    __syncthreads();
    out[b * T_ + tid] = out_lds[tid];
}

extern "C" void kernel_launch(void* const* d_in, const int* in_sizes, int n_in,
                              void* d_out, int out_size, void* d_ws, size_t ws_size,
                              hipStream_t stream) {
    const float* xd   = (const float*)d_in[0];
    const float* xs   = (const float*)d_in[1];
    const float* Wih  = (const float*)d_in[2];
    const float* Whh  = (const float*)d_in[3];
    const float* Wzh  = (const float*)d_in[4];
    const float* bias = (const float*)d_in[5];
    const float* Wout = (const float*)d_in[6];
    const float* bout = (const float*)d_in[7];
    float* o = (float*)d_out;
    hipLaunchKernelGGL(tamlstm_kernel, dim3(B_), dim3(512), 0, stream,
                       xd, xs, Wih, Whh, Wzh, bias, Wout, bout, o);
}